// Round 9
// baseline (120.495 us; speedup 1.0000x reference)
//
#include <hip/hip_runtime.h>
#include <float.h>

#define B_CONST 8
#define GROUPS 8          // ref-dim split across blocks (combined in hd_final)
#define QSPLIT 8          // query-dim split of the final reduce
#define REPS 3            // instrumentation: run hot body 3x in one dispatch

typedef float v2f __attribute__((ext_vector_type(2)));

// INSTRUMENTATION ROUND: identical to r8 except the whole body executes REPS
// times (idempotent redo) so the hot kernel's duration exceeds the 40us fill
// dispatches and its counter row becomes visible in the top-5.
// t_nnmax = (total_r9 - total_r8) / (REPS - 1).
__global__ __launch_bounds__(256) void hd_nnmax(
    const float* __restrict__ p1raw, const float* __restrict__ p2raw,
    float* __restrict__ part, unsigned int* __restrict__ comm,
    int N, int M, int blocksDir0) {
  for (int rep = 0; rep < REPS; ++rep) {
    int blk = blockIdx.x;
    if (blk == 0 && threadIdx.x < 9) comm[threadIdx.x] = 0u;

    const float* qraw; const float* rraw; int QN, RM, dir;
    if (blk < blocksDir0) { qraw = p1raw; rraw = p2raw; QN = N; RM = M; dir = 0; }
    else { blk -= blocksDir0; qraw = p2raw; rraw = p1raw; QN = M; RM = N; dir = 1; }

    int qblocks = QN >> 9;                       // 512 queries per block
    int perB = qblocks * GROUPS;
    int b    = blk / perB;
    int rem  = blk - b * perB;
    int qblk = rem / GROUPS;
    int g    = rem - qblk * GROUPS;

    int l = threadIdx.x & 63;
    int w = __builtin_amdgcn_readfirstlane((int)(threadIdx.x >> 6));   // 0..3

    __shared__ float buf[2048];                  // tile (8KB), reused as red
    __shared__ float qw_s[512];                  // |q|^2 per query-in-block

    // Stage + pack this group's 512 refs: thread i packs pair i (refs 2i,2i+1).
    int refsPerGroup = RM / GROUPS;              // 512
    const float* rsrc = rraw + 3 * ((size_t)b * RM + (size_t)g * refsPerGroup);
    {
        int i = threadIdx.x;                     // pair index 0..255
        float x0 = rsrc[6*i],   y0 = rsrc[6*i+1], z0 = rsrc[6*i+2];
        float x1 = rsrc[6*i+3], y1 = rsrc[6*i+4], z1 = rsrc[6*i+5];
        float* t = buf + 8 * i;
        t[0] = -2.0f * x0; t[1] = -2.0f * x1;
        t[2] = -2.0f * y0; t[3] = -2.0f * y1;
        t[4] = -2.0f * z0; t[5] = -2.0f * z1;
        t[6] = fmaf(x0, x0, fmaf(y0, y0, z0 * z0));
        t[7] = fmaf(x1, x1, fmaf(y1, y1, z1 * z1));
    }

    // 8 queries/thread from raw input (q depends only on lane -> all 4 waves
    // load the same 512 queries, L1-served). Wave 0 stashes |q|^2.
    const float* qb = qraw + 3 * ((size_t)b * QN + ((size_t)qblk << 9));
    v2f QX[8], QY[8], QZ[8], MN[8];
    #pragma unroll
    for (int s = 0; s < 8; ++s) {
        int q = s * 64 + l;
        float x = qb[3*q], y = qb[3*q+1], z = qb[3*q+2];
        QX[s] = (v2f){ x, x };
        QY[s] = (v2f){ y, y };
        QZ[s] = (v2f){ z, z };
        MN[s] = (v2f){ FLT_MAX, FLT_MAX };
        if (w == 0) qw_s[q] = fmaf(x, x, fmaf(y, y, z * z));
    }
    __syncthreads();

    // Wave w scans pairs [w*64, w*64+64) from LDS (uniform-address broadcast).
    const v2f* lp = (const v2f*)buf + (size_t)(w * 64) * 4;
    #pragma unroll 4
    for (int j = 0; j < 64; ++j) {
        v2f RX = lp[4*j + 0];
        v2f RY = lp[4*j + 1];
        v2f RZ = lp[4*j + 2];
        v2f RW = lp[4*j + 3];
        #pragma unroll
        for (int s = 0; s < 8; ++s) {
            v2f a = __builtin_elementwise_fma(QX[s], RX, RW);
            a = __builtin_elementwise_fma(QY[s], RY, a);
            a = __builtin_elementwise_fma(QZ[s], RZ, a);
            MN[s] = __builtin_elementwise_min(MN[s], a);
        }
    }
    __syncthreads();                             // tile reads done; reuse buf

    // Combine the 4 wave-partials per query in LDS (buf reused as red[2048]).
    #pragma unroll
    for (int s = 0; s < 8; ++s)
        buf[(w << 9) + s * 64 + l] = fminf(MN[s].x, MN[s].y);
    __syncthreads();

    // part[dir][g][b][query]: plain coalesced stores, combined in hd_final.
    size_t dirOff = dir ? (size_t)GROUPS * B_CONST * N : 0;
    float* pb = part + dirOff + ((size_t)g * B_CONST + b) * QN + ((size_t)qblk << 9);
    for (int t = threadIdx.x; t < 512; t += 256) {
        float m = fminf(fminf(buf[t], buf[512 + t]),
                        fminf(buf[1024 + t], buf[1536 + t]));
        pb[t] = fmaxf(qw_s[t] + m, 0.0f);        // min over this ref group
    }
    __syncthreads();                             // LDS reuse across reps
  }
}

// 128 blocks: one per (dir, b, query-slice). min over GROUPS partials, max over
// the query slice, atomicMax into comm[b]; global ticket 127 sums into out[0].
__global__ __launch_bounds__(256) void hd_final(
    const float* __restrict__ part, unsigned int* __restrict__ comm,
    float* __restrict__ out, int N, int M) {
    int db  = blockIdx.x >> 3;                  // 0..15
    int qs  = blockIdx.x & (QSPLIT - 1);
    int dir = db >> 3;
    int b   = db & 7;
    int QN  = dir ? M : N;
    size_t dirOff = dir ? (size_t)GROUPS * B_CONST * N : 0;
    const float* fb = part + dirOff + (size_t)b * QN;
    size_t gs = (size_t)B_CONST * QN;

    int span = QN / QSPLIT;
    int q0 = qs * span;
    float mx = 0.0f;
    for (int qq = q0 + threadIdx.x; qq < q0 + span; qq += 256) {
        float mm = fb[qq];
        #pragma unroll
        for (int gg = 1; gg < GROUPS; ++gg)
            mm = fminf(mm, fb[(size_t)gg * gs + qq]);
        mx = fmaxf(mx, mm);
    }
    #pragma unroll
    for (int off = 32; off > 0; off >>= 1)
        mx = fmaxf(mx, __shfl_down(mx, off, 64));
    __shared__ float wred[4];
    int l = threadIdx.x & 63, w = threadIdx.x >> 6;
    if (l == 0) wred[w] = mx;
    __syncthreads();
    if (threadIdx.x == 0) {
        mx = fmaxf(fmaxf(wred[0], wred[1]), fmaxf(wred[2], wred[3]));
        atomicMax(&comm[b], __float_as_uint(mx));   // covers both dirs + slices
        __threadfence();
        unsigned int t2 = atomicAdd(&comm[8], 1u);
        if (t2 == (unsigned int)(16 * QSPLIT - 1)) {
            float s = 0.0f;
            for (int bb = 0; bb < B_CONST; ++bb)
                s += __uint_as_float(atomicMax(&comm[bb], 0u));  // coherent read
            out[0] = s;
        }
    }
}

extern "C" void kernel_launch(void* const* d_in, const int* in_sizes, int n_in,
                              void* d_out, int out_size, void* d_ws, size_t ws_size,
                              hipStream_t stream) {
    const float* p1 = (const float*)d_in[0];
    const float* p2 = (const float*)d_in[1];
    const int B = B_CONST;
    int N = in_sizes[0] / (3 * B);
    int M = in_sizes[1] / (3 * B);
    int n1 = B * N, n2 = B * M;

    char* ws = (char*)d_ws;
    float* part = (float*)ws;                    // GROUPS*(n1+n2) floats = 2MB
    unsigned int* comm = (unsigned int*)(part + (size_t)GROUPS * (n1 + n2));

    int blocksDir0 = B * (N >> 9) * GROUPS;      // 512 per dir
    int blocksDir1 = B * (M >> 9) * GROUPS;
    hd_nnmax<<<blocksDir0 + blocksDir1, 256, 0, stream>>>(
        p1, p2, part, comm, N, M, blocksDir0);

    hd_final<<<16 * QSPLIT, 256, 0, stream>>>(part, comm, (float*)d_out, N, M);
}

// Round 10
// 80.146 us; speedup vs baseline: 1.5034x; 1.5034x over previous
//
#include <hip/hip_runtime.h>
#include <float.h>

#define B_CONST 8
#define GROUPS 8          // ref-dim split across blocks (combined in hd_final)
#define QSPLIT 8          // query-dim split of the final reduce

typedef float v2f __attribute__((ext_vector_type(2)));

// Forced packed FP32 FMA: r9 instrumentation proved the compiler scalarized
// __builtin_elementwise_fma on v2f (VALU cycles matched the 8-instr scalar
// model exactly). v_pk_fma_f32 halves the fma issue count.
__device__ __forceinline__ v2f pk_fma(v2f a, v2f b, v2f c) {
    v2f d;
    asm("v_pk_fma_f32 %0, %1, %2, %3" : "=v"(d) : "v"(a), "v"(b), "v"(c));
    return d;
}

// Block = 512 queries (64 lanes x Q=8) x one ref group of 512 points.
// Refs staged raw->LDS as packed SoA pairs with -2 prefolded (8KB tile).
// Per pair per query: 3 v_pk_fma_f32 + 2 v_min_f32 (5 instr / 2 points).
// Cross-wave combine reuses tile LDS; plain coalesced partial stores.
__global__ __launch_bounds__(256) void hd_nnmax(
    const float* __restrict__ p1raw, const float* __restrict__ p2raw,
    float* __restrict__ part, unsigned int* __restrict__ comm,
    int N, int M, int blocksDir0) {
    int blk = blockIdx.x;
    if (blk == 0 && threadIdx.x < 9) comm[threadIdx.x] = 0u;

    const float* qraw; const float* rraw; int QN, RM, dir;
    if (blk < blocksDir0) { qraw = p1raw; rraw = p2raw; QN = N; RM = M; dir = 0; }
    else { blk -= blocksDir0; qraw = p2raw; rraw = p1raw; QN = M; RM = N; dir = 1; }

    int qblocks = QN >> 9;                       // 512 queries per block
    int perB = qblocks * GROUPS;
    int b    = blk / perB;
    int rem  = blk - b * perB;
    int qblk = rem / GROUPS;
    int g    = rem - qblk * GROUPS;

    int l = threadIdx.x & 63;
    int w = __builtin_amdgcn_readfirstlane((int)(threadIdx.x >> 6));   // 0..3

    __shared__ float buf[2048];                  // tile (8KB), reused as red
    __shared__ float qw_s[512];                  // |q|^2 per query-in-block

    // Stage + pack this group's 512 refs: thread i packs pair i (refs 2i,2i+1).
    int refsPerGroup = RM / GROUPS;              // 512
    const float* rsrc = rraw + 3 * ((size_t)b * RM + (size_t)g * refsPerGroup);
    {
        int i = threadIdx.x;                     // pair index 0..255
        float x0 = rsrc[6*i],   y0 = rsrc[6*i+1], z0 = rsrc[6*i+2];
        float x1 = rsrc[6*i+3], y1 = rsrc[6*i+4], z1 = rsrc[6*i+5];
        float* t = buf + 8 * i;
        t[0] = -2.0f * x0; t[1] = -2.0f * x1;
        t[2] = -2.0f * y0; t[3] = -2.0f * y1;
        t[4] = -2.0f * z0; t[5] = -2.0f * z1;
        t[6] = fmaf(x0, x0, fmaf(y0, y0, z0 * z0));
        t[7] = fmaf(x1, x1, fmaf(y1, y1, z1 * z1));
    }

    // 8 queries/thread from raw input (same 512 queries for all 4 waves,
    // L1-served). Wave 0 stashes |q|^2.
    const float* qb = qraw + 3 * ((size_t)b * QN + ((size_t)qblk << 9));
    v2f QX[8], QY[8], QZ[8];
    float mA[8], mB[8];
    #pragma unroll
    for (int s = 0; s < 8; ++s) {
        int q = s * 64 + l;
        float x = qb[3*q], y = qb[3*q+1], z = qb[3*q+2];
        QX[s] = (v2f){ x, x };
        QY[s] = (v2f){ y, y };
        QZ[s] = (v2f){ z, z };
        mA[s] = FLT_MAX; mB[s] = FLT_MAX;
        if (w == 0) qw_s[q] = fmaf(x, x, fmaf(y, y, z * z));
    }
    __syncthreads();

    // Wave w scans pairs [w*64, w*64+64) from LDS (uniform-address broadcast).
    const v2f* lp = (const v2f*)buf + (size_t)(w * 64) * 4;
    #pragma unroll 4
    for (int j = 0; j < 64; ++j) {
        v2f RX = lp[4*j + 0];
        v2f RY = lp[4*j + 1];
        v2f RZ = lp[4*j + 2];
        v2f RW = lp[4*j + 3];
        #pragma unroll
        for (int s = 0; s < 8; ++s) {
            v2f a = pk_fma(QX[s], RX, RW);
            a = pk_fma(QY[s], RY, a);
            a = pk_fma(QZ[s], RZ, a);
            mA[s] = fminf(mA[s], a.x);
            mB[s] = fminf(mB[s], a.y);
        }
    }
    __syncthreads();                             // tile reads done; reuse buf

    // Combine the 4 wave-partials per query in LDS (buf reused as red[2048]).
    #pragma unroll
    for (int s = 0; s < 8; ++s)
        buf[(w << 9) + s * 64 + l] = fminf(mA[s], mB[s]);
    __syncthreads();

    // part[dir][g][b][query]: plain coalesced stores, combined in hd_final.
    size_t dirOff = dir ? (size_t)GROUPS * B_CONST * N : 0;
    float* pb = part + dirOff + ((size_t)g * B_CONST + b) * QN + ((size_t)qblk << 9);
    for (int t = threadIdx.x; t < 512; t += 256) {
        float m = fminf(fminf(buf[t], buf[512 + t]),
                        fminf(buf[1024 + t], buf[1536 + t]));
        pb[t] = fmaxf(qw_s[t] + m, 0.0f);        // min over this ref group
    }
}

// 128 blocks: one per (dir, b, query-slice). min over GROUPS partials, max over
// the query slice, atomicMax into comm[b]; global ticket 127 sums into out[0].
__global__ __launch_bounds__(256) void hd_final(
    const float* __restrict__ part, unsigned int* __restrict__ comm,
    float* __restrict__ out, int N, int M) {
    int db  = blockIdx.x >> 3;                  // 0..15
    int qs  = blockIdx.x & (QSPLIT - 1);
    int dir = db >> 3;
    int b   = db & 7;
    int QN  = dir ? M : N;
    size_t dirOff = dir ? (size_t)GROUPS * B_CONST * N : 0;
    const float* fb = part + dirOff + (size_t)b * QN;
    size_t gs = (size_t)B_CONST * QN;

    int span = QN / QSPLIT;
    int q0 = qs * span;
    float mx = 0.0f;
    for (int qq = q0 + threadIdx.x; qq < q0 + span; qq += 256) {
        float mm = fb[qq];
        #pragma unroll
        for (int gg = 1; gg < GROUPS; ++gg)
            mm = fminf(mm, fb[(size_t)gg * gs + qq]);
        mx = fmaxf(mx, mm);
    }
    #pragma unroll
    for (int off = 32; off > 0; off >>= 1)
        mx = fmaxf(mx, __shfl_down(mx, off, 64));
    __shared__ float wred[4];
    int l = threadIdx.x & 63, w = threadIdx.x >> 6;
    if (l == 0) wred[w] = mx;
    __syncthreads();
    if (threadIdx.x == 0) {
        mx = fmaxf(fmaxf(wred[0], wred[1]), fmaxf(wred[2], wred[3]));
        atomicMax(&comm[b], __float_as_uint(mx));   // covers both dirs + slices
        __threadfence();
        unsigned int t2 = atomicAdd(&comm[8], 1u);
        if (t2 == (unsigned int)(16 * QSPLIT - 1)) {
            float s = 0.0f;
            for (int bb = 0; bb < B_CONST; ++bb)
                s += __uint_as_float(atomicMax(&comm[bb], 0u));  // coherent read
            out[0] = s;
        }
    }
}

extern "C" void kernel_launch(void* const* d_in, const int* in_sizes, int n_in,
                              void* d_out, int out_size, void* d_ws, size_t ws_size,
                              hipStream_t stream) {
    const float* p1 = (const float*)d_in[0];
    const float* p2 = (const float*)d_in[1];
    const int B = B_CONST;
    int N = in_sizes[0] / (3 * B);
    int M = in_sizes[1] / (3 * B);
    int n1 = B * N, n2 = B * M;

    char* ws = (char*)d_ws;
    float* part = (float*)ws;                    // GROUPS*(n1+n2) floats = 2MB
    unsigned int* comm = (unsigned int*)(part + (size_t)GROUPS * (n1 + n2));

    int blocksDir0 = B * (N >> 9) * GROUPS;      // 512 per dir
    int blocksDir1 = B * (M >> 9) * GROUPS;
    hd_nnmax<<<blocksDir0 + blocksDir1, 256, 0, stream>>>(
        p1, p2, part, comm, N, M, blocksDir0);

    hd_final<<<16 * QSPLIT, 256, 0, stream>>>(part, comm, (float*)d_out, N, M);
}